// Round 1
// baseline (242.831 us; speedup 1.0000x reference)
//
#include <hip/hip_runtime.h>

#define NBINS 256
#define TILE  128          // tile is 128x128 -> 16384 pixels
#define CLIPV 2560u        // max(40 * 16384 // 256, 1)

// ---------------------------------------------------------------------------
// Kernel 1: per-tile histogram -> clip -> redistribute -> cumsum -> LUT
// One block per tile (1536 = 8*3*8*8), 256 threads (4 waves).
// ---------------------------------------------------------------------------
__global__ __launch_bounds__(256) void clahe_hist_lut(
        const float* __restrict__ x, float* __restrict__ lut) {
    const int t   = blockIdx.x;          // tile id: ((b*3+c)*8+ty)*8+tx
    const int tid = threadIdx.x;
    const int wave = tid >> 6;

    __shared__ unsigned int h[4][NBINS];   // per-wave histograms
    __shared__ int          scan[2][NBINS];
    __shared__ unsigned int wsum[4];

    h[0][tid] = 0; h[1][tid] = 0; h[2][tid] = 0; h[3][tid] = 0;
    __syncthreads();

    const int tx = t & 7;
    const int ty = (t >> 3) & 7;
    const int bc = t >> 6;
    const float* base = x + ((size_t)bc * 1024 + (size_t)ty * TILE) * 1024
                          + (size_t)tx * TILE;

    const int lane32 = tid & 31;   // float4 column within the tile row
    const int rgrp   = tid >> 5;   // 0..7 -> 8 rows covered per iteration
    #pragma unroll 4
    for (int rr = 0; rr < 16; ++rr) {
        const int row = rr * 8 + rgrp;
        const float4 v = *(const float4*)(base + (size_t)row * 1024 + lane32 * 4);
        int b0 = min(max((int)(v.x * 256.0f), 0), 255);
        int b1 = min(max((int)(v.y * 256.0f), 0), 255);
        int b2 = min(max((int)(v.z * 256.0f), 0), 255);
        int b3 = min(max((int)(v.w * 256.0f), 0), 255);
        atomicAdd(&h[wave][b0], 1u);
        atomicAdd(&h[wave][b1], 1u);
        atomicAdd(&h[wave][b2], 1u);
        atomicAdd(&h[wave][b3], 1u);
    }
    __syncthreads();

    const unsigned int total  = h[0][tid] + h[1][tid] + h[2][tid] + h[3][tid];
    const unsigned int hv     = min(total, CLIPV);
    unsigned int e = total - hv;               // excess clipped from this bin
    // wave=64 reduction of excess
    #pragma unroll
    for (int off = 32; off > 0; off >>= 1) e += __shfl_down(e, off, 64);
    if ((tid & 63) == 0) wsum[wave] = e;
    __syncthreads();
    const unsigned int E        = wsum[0] + wsum[1] + wsum[2] + wsum[3];
    const unsigned int add      = E >> 8;      // (clipped - residual)/256
    const unsigned int residual = E & 255u;    // clipped mod 256
    const int h2 = (int)(hv + add + ((unsigned)tid < residual ? 1u : 0u));

    // inclusive scan over 256 bins (Hillis-Steele, ping-pong)
    scan[0][tid] = h2;
    __syncthreads();
    int src = 0;
    #pragma unroll
    for (int off = 1; off < 256; off <<= 1) {
        int v = scan[src][tid];
        if (tid >= off) v += scan[src][tid - off];
        scan[src ^ 1][tid] = v;
        __syncthreads();
        src ^= 1;
    }
    const int cum = scan[src][tid];
    // 255/16384 = 255 * 2^-14: fp32 multiply is exact here (cum*255 < 2^22)
    const float l = fminf((float)cum * (255.0f / 16384.0f), 255.0f);
    lut[(size_t)t * NBINS + tid] = floorf(l);
}

// ---------------------------------------------------------------------------
// Kernel 2: bilinear LUT interpolation, one thread per float4 of output.
// ---------------------------------------------------------------------------
__global__ __launch_bounds__(256) void clahe_apply(
        const float* __restrict__ x, const float* __restrict__ lut,
        float* __restrict__ out) {
    const size_t i = (size_t)blockIdx.x * 256 + threadIdx.x; // float4 index
    const int bc  = (int)(i >> 18);        // / (1024*1024/4)
    const int rem = (int)(i & 262143);
    const int y   = rem >> 8;              // row 0..1023
    const int x4  = rem & 255;             // float4 col 0..255

    // row-axis interpolation coords (half = 64, denom = 127)
    const int j = y >> 6, p = y & 63;
    int r0 = (j - 1) >> 1;                 // matches Python floor division
    r0 = min(max(r0, 0), 7);
    const int r1 = min(r0 + 1, 7);
    const float wy = (j == 0) ? 1.0f
                   : (float)((j & 1) ? (127 - p) : (63 - p)) / 127.0f;

    const float4 v = *(const float4*)(x + i * 4);
    const float* lbase = lut + (size_t)bc * 64 * NBINS;
    const size_t ro0 = (size_t)r0 * 8 * NBINS;
    const size_t ro1 = (size_t)r1 * 8 * NBINS;

    float res[4];
    const float vv[4] = {v.x, v.y, v.z, v.w};
    #pragma unroll
    for (int k = 0; k < 4; ++k) {
        const int xx = x4 * 4 + k;
        const int jc = xx >> 6, pc = xx & 63;
        int c0 = (jc - 1) >> 1;
        c0 = min(max(c0, 0), 7);
        const int c1 = min(c0 + 1, 7);
        const float wx = (jc == 0) ? 1.0f
                       : (float)((jc & 1) ? (127 - pc) : (63 - pc)) / 127.0f;
        const int idx = min(max((int)(vv[k] * 255.0f), 0), 255);

        const float g00 = lbase[ro0 + (size_t)c0 * NBINS + idx];
        const float g01 = lbase[ro0 + (size_t)c1 * NBINS + idx];
        const float g10 = lbase[ro1 + (size_t)c0 * NBINS + idx];
        const float g11 = lbase[ro1 + (size_t)c1 * NBINS + idx];

        const float o = wy * wx * g00 + wy * (1.0f - wx) * g01
                      + (1.0f - wy) * wx * g10 + (1.0f - wy) * (1.0f - wx) * g11;
        res[k] = o / 255.0f;
    }
    float4 o4 = make_float4(res[0], res[1], res[2], res[3]);
    *(float4*)(out + i * 4) = o4;
}

extern "C" void kernel_launch(void* const* d_in, const int* in_sizes, int n_in,
                              void* d_out, int out_size, void* d_ws, size_t ws_size,
                              hipStream_t stream) {
    const float* x = (const float*)d_in[0];
    float* out = (float*)d_out;
    float* lut = (float*)d_ws;   // 1536 * 256 floats = 1.57 MB

    clahe_hist_lut<<<1536, 256, 0, stream>>>(x, lut);
    // 8*3*1024*1024 / 4 floats per thread = 6291456 threads = 24576 blocks
    clahe_apply<<<24576, 256, 0, stream>>>(x, lut, out);
}

// Round 2
// 195.906 us; speedup vs baseline: 1.2395x; 1.2395x over previous
//
#include <hip/hip_runtime.h>

#define NBINS 256
#define TILE  128          // tile is 128x128 -> 16384 pixels
#define CLIPV 2560u        // max(40 * 16384 // 256, 1)

// ---------------------------------------------------------------------------
// Kernel 1: per-tile histogram -> clip -> redistribute -> cumsum -> LUT
// One block per tile (1536 = 8*3*8*8), 256 threads (4 waves).
// 8-way bin-major sub-histograms: hs[bin*8 + (tid&7)] -> bank (8*bin+sub)%32,
// so bank collisions only among the 8 lanes sharing sub (~2-way, free) and
// same-address atomic serialization is rare.
// ---------------------------------------------------------------------------
__global__ __launch_bounds__(256) void clahe_hist_lut(
        const float* __restrict__ x, float* __restrict__ lut) {
    const int t   = blockIdx.x;          // tile id: ((b*3+c)*8+ty)*8+tx
    const int tid = threadIdx.x;

    __shared__ unsigned int hs[NBINS * 8];   // bin-major interleaved
    __shared__ int          scan[2][NBINS];
    __shared__ unsigned int wsum[4];

    #pragma unroll
    for (int k = 0; k < 8; ++k) hs[k * NBINS + tid] = 0u;
    __syncthreads();

    const int tx = t & 7;
    const int ty = (t >> 3) & 7;
    const int bc = t >> 6;
    const float* base = x + ((size_t)bc * 1024 + (size_t)ty * TILE) * 1024
                          + (size_t)tx * TILE;

    const int sub    = tid & 7;
    const int lane32 = tid & 31;   // float4 column within the tile row
    const int rgrp   = tid >> 5;   // 0..7 -> 8 rows covered per iteration
    #pragma unroll 4
    for (int rr = 0; rr < 16; ++rr) {
        const int row = rr * 8 + rgrp;
        const float4 v = *(const float4*)(base + (size_t)row * 1024 + lane32 * 4);
        int b0 = min(max((int)(v.x * 256.0f), 0), 255);
        int b1 = min(max((int)(v.y * 256.0f), 0), 255);
        int b2 = min(max((int)(v.z * 256.0f), 0), 255);
        int b3 = min(max((int)(v.w * 256.0f), 0), 255);
        atomicAdd(&hs[b0 * 8 + sub], 1u);
        atomicAdd(&hs[b1 * 8 + sub], 1u);
        atomicAdd(&hs[b2 * 8 + sub], 1u);
        atomicAdd(&hs[b3 * 8 + sub], 1u);
    }
    __syncthreads();

    // gather the 8 sub-counts for bin `tid`
    const uint4* hp = (const uint4*)(&hs[tid * 8]);
    const uint4 ha = hp[0], hb = hp[1];
    const unsigned int total = ha.x + ha.y + ha.z + ha.w
                             + hb.x + hb.y + hb.z + hb.w;
    const unsigned int hv = min(total, CLIPV);
    unsigned int e = total - hv;               // excess clipped from this bin
    #pragma unroll
    for (int off = 32; off > 0; off >>= 1) e += __shfl_down(e, off, 64);
    if ((tid & 63) == 0) wsum[tid >> 6] = e;
    __syncthreads();
    const unsigned int E        = wsum[0] + wsum[1] + wsum[2] + wsum[3];
    const unsigned int add      = E >> 8;      // (clipped - residual)/256
    const unsigned int residual = E & 255u;    // clipped mod 256
    const int h2 = (int)(hv + add + ((unsigned)tid < residual ? 1u : 0u));

    // inclusive scan over 256 bins (Hillis-Steele, ping-pong)
    scan[0][tid] = h2;
    __syncthreads();
    int src = 0;
    #pragma unroll
    for (int off = 1; off < 256; off <<= 1) {
        int v = scan[src][tid];
        if (tid >= off) v += scan[src][tid - off];
        scan[src ^ 1][tid] = v;
        __syncthreads();
        src ^= 1;
    }
    const int cum = scan[src][tid];
    // 255/16384 = 255 * 2^-14: fp32 multiply is exact here (cum*255 < 2^22)
    const float l = fminf((float)cum * (255.0f / 16384.0f), 255.0f);
    lut[(size_t)t * NBINS + tid] = floorf(l);
}

// ---------------------------------------------------------------------------
// Kernel 2: bilinear LUT interpolation.
// One block per (bc, 8-row slab): r0/r1 are uniform over the slab (8 | 64),
// so the 2 x 8 x 256 LUT entries the slab needs are staged in LDS (16 KB)
// and all 4 taps/pixel become random-bank ds_read_b32 (~2-way aliasing).
// Thread t owns float4-column t for all 8 rows -> fully coalesced rows.
// ---------------------------------------------------------------------------
__global__ __launch_bounds__(256) void clahe_apply(
        const float* __restrict__ x, const float* __restrict__ lut,
        float* __restrict__ out) {
    __shared__ float l0[8 * NBINS];   // LUT row r0, all 8 column tiles
    __shared__ float l1[8 * NBINS];   // LUT row r1

    const int blk = blockIdx.x;
    const int bc  = blk >> 7;          // 128 row-groups per image plane
    const int rg  = blk & 127;
    const int y0  = rg * 8;
    const int tid = threadIdx.x;

    // row-axis interpolation coords (half = 64, denom = 127) — slab-uniform
    const int j = y0 >> 6;
    int r0 = (j - 1) >> 1;             // matches Python floor division
    r0 = min(max(r0, 0), 7);
    const int r1 = min(r0 + 1, 7);

    // stage LUTs: 2 x 2048 floats = 512 + 512 float4
    {
        const float* lb = lut + (size_t)bc * 64 * NBINS;
        const float4* s0 = (const float4*)(lb + (size_t)r0 * 8 * NBINS);
        const float4* s1 = (const float4*)(lb + (size_t)r1 * 8 * NBINS);
        ((float4*)l0)[tid]       = s0[tid];
        ((float4*)l0)[tid + 256] = s0[tid + 256];
        ((float4*)l1)[tid]       = s1[tid];
        ((float4*)l1)[tid + 256] = s1[tid + 256];
    }
    __syncthreads();

    // column-axis params for this thread's 4 columns (fixed across rows)
    int c0k[4], c1k[4];
    float wxk[4];
    #pragma unroll
    for (int k = 0; k < 4; ++k) {
        const int xx = tid * 4 + k;
        const int jc = xx >> 6, pc = xx & 63;
        int c0 = (jc - 1) >> 1;
        c0 = min(max(c0, 0), 7);
        c0k[k] = c0;
        c1k[k] = min(c0 + 1, 7);
        wxk[k] = (jc == 0) ? 1.0f
               : (float)((jc & 1) ? (127 - pc) : (63 - pc)) / 127.0f;
    }

    const bool jzero = (j == 0);
    const bool jodd  = (j & 1);
    const size_t rowbase = ((size_t)bc * 1024 + (size_t)y0) * 1024 + tid * 4;

    #pragma unroll
    for (int r = 0; r < 8; ++r) {
        const int p = (y0 + r) & 63;
        const float wy = jzero ? 1.0f
                       : (float)(jodd ? (127 - p) : (63 - p)) / 127.0f;

        const float4 v = *(const float4*)(x + rowbase + (size_t)r * 1024);
        const float vv[4] = {v.x, v.y, v.z, v.w};
        float res[4];
        #pragma unroll
        for (int k = 0; k < 4; ++k) {
            const int idx = min(max((int)(vv[k] * 255.0f), 0), 255);
            const int o0 = c0k[k] * NBINS + idx;
            const int o1 = c1k[k] * NBINS + idx;
            const float g00 = l0[o0];
            const float g01 = l0[o1];
            const float g10 = l1[o0];
            const float g11 = l1[o1];
            const float wx = wxk[k];
            const float o = wy * wx * g00 + wy * (1.0f - wx) * g01
                          + (1.0f - wy) * wx * g10 + (1.0f - wy) * (1.0f - wx) * g11;
            res[k] = o / 255.0f;
        }
        *(float4*)(out + rowbase + (size_t)r * 1024) =
            make_float4(res[0], res[1], res[2], res[3]);
    }
}

extern "C" void kernel_launch(void* const* d_in, const int* in_sizes, int n_in,
                              void* d_out, int out_size, void* d_ws, size_t ws_size,
                              hipStream_t stream) {
    const float* x = (const float*)d_in[0];
    float* out = (float*)d_out;
    float* lut = (float*)d_ws;   // 1536 * 256 floats = 1.57 MB

    clahe_hist_lut<<<1536, 256, 0, stream>>>(x, lut);
    // 24 planes * 128 8-row slabs
    clahe_apply<<<24 * 128, 256, 0, stream>>>(x, lut, out);
}

// Round 4
// 189.955 us; speedup vs baseline: 1.2784x; 1.0313x over previous
//
#include <hip/hip_runtime.h>

#define NBINS 256
#define TILE  128          // tile is 128x128 -> 16384 pixels
#define CLIPV 2560u        // max(40 * 16384 // 256, 1)

typedef float  fx4 __attribute__((ext_vector_type(4)));   // native vec for nontemporal ops
typedef float  fx2 __attribute__((ext_vector_type(2)));

// ---------------------------------------------------------------------------
// Kernel 1: per-tile histogram -> clip -> redistribute -> cumsum -> LUT
// One block per tile (1536 = 8*3*8*8), 256 threads (4 waves).
// 8-way bin-major sub-histograms: hs[bin*8 + (tid&7)] -> bank (8*bin+sub)%32,
// random bins spread ~2 lanes/bank (free per m136), and same-address atomic
// serialization is rare.
// ---------------------------------------------------------------------------
__global__ __launch_bounds__(256) void clahe_hist_lut(
        const float* __restrict__ x, float* __restrict__ lut) {
    const int t   = blockIdx.x;          // tile id: ((b*3+c)*8+ty)*8+tx
    const int tid = threadIdx.x;

    __shared__ unsigned int hs[NBINS * 8];   // bin-major interleaved
    __shared__ int          scan[2][NBINS];
    __shared__ unsigned int wsum[4];

    #pragma unroll
    for (int k = 0; k < 8; ++k) hs[k * NBINS + tid] = 0u;
    __syncthreads();

    const int tx = t & 7;
    const int ty = (t >> 3) & 7;
    const int bc = t >> 6;
    const float* base = x + ((size_t)bc * 1024 + (size_t)ty * TILE) * 1024
                          + (size_t)tx * TILE;

    const int sub    = tid & 7;
    const int lane32 = tid & 31;   // float4 column within the tile row
    const int rgrp   = tid >> 5;   // 0..7 -> 8 rows covered per iteration
    #pragma unroll 4
    for (int rr = 0; rr < 16; ++rr) {
        const int row = rr * 8 + rgrp;
        const fx4 v = __builtin_nontemporal_load(
            (const fx4*)(base + (size_t)row * 1024 + lane32 * 4));
        int b0 = min(max((int)(v.x * 256.0f), 0), 255);
        int b1 = min(max((int)(v.y * 256.0f), 0), 255);
        int b2 = min(max((int)(v.z * 256.0f), 0), 255);
        int b3 = min(max((int)(v.w * 256.0f), 0), 255);
        atomicAdd(&hs[b0 * 8 + sub], 1u);
        atomicAdd(&hs[b1 * 8 + sub], 1u);
        atomicAdd(&hs[b2 * 8 + sub], 1u);
        atomicAdd(&hs[b3 * 8 + sub], 1u);
    }
    __syncthreads();

    // gather the 8 sub-counts for bin `tid`
    const uint4* hp = (const uint4*)(&hs[tid * 8]);
    const uint4 ha = hp[0], hb = hp[1];
    const unsigned int total = ha.x + ha.y + ha.z + ha.w
                             + hb.x + hb.y + hb.z + hb.w;
    const unsigned int hv = min(total, CLIPV);
    unsigned int e = total - hv;               // excess clipped from this bin
    #pragma unroll
    for (int off = 32; off > 0; off >>= 1) e += __shfl_down(e, off, 64);
    if ((tid & 63) == 0) wsum[tid >> 6] = e;
    __syncthreads();
    const unsigned int E        = wsum[0] + wsum[1] + wsum[2] + wsum[3];
    const unsigned int add      = E >> 8;      // (clipped - residual)/256
    const unsigned int residual = E & 255u;    // clipped mod 256
    const int h2 = (int)(hv + add + ((unsigned)tid < residual ? 1u : 0u));

    // inclusive scan over 256 bins (Hillis-Steele, ping-pong)
    scan[0][tid] = h2;
    __syncthreads();
    int src = 0;
    #pragma unroll
    for (int off = 1; off < 256; off <<= 1) {
        int v = scan[src][tid];
        if (tid >= off) v += scan[src][tid - off];
        scan[src ^ 1][tid] = v;
        __syncthreads();
        src ^= 1;
    }
    const int cum = scan[src][tid];
    // 255/16384 = 255 * 2^-14: fp32 multiply is exact here (cum*255 < 2^22)
    const float l = fminf((float)cum * (255.0f / 16384.0f), 255.0f);
    lut[(size_t)t * NBINS + tid] = floorf(l);
}

// ---------------------------------------------------------------------------
// Kernel 2: bilinear LUT interpolation.
// One block per (bc, 16-row group). 16 | 64 so the whole group shares j and
// thus (r0, r1). The two LUT tile-rows (2 x 2048 floats) are staged in LDS
// INTERLEAVED as float2 {l0, l1}: the (g00,g10) / (g01,g11) tap pairs become
// single ds_read_b64 ops -> 2 LDS instructions per pixel instead of 4.
// Thread t owns float4-column t for all 16 rows -> fully coalesced rows.
// x / out traffic is nontemporal (streaming; keep L2 for the LUT).
// ---------------------------------------------------------------------------
__global__ __launch_bounds__(256) void clahe_apply(
        const float* __restrict__ x, const float* __restrict__ lut,
        float* __restrict__ out) {
    __shared__ fx4 l01s[1024];         // 2048 fx2 entries {l0[i], l1[i]}

    const int blk = blockIdx.x;
    const int bc  = blk >> 6;          // 64 16-row groups per image plane
    const int rg  = blk & 63;
    const int y0  = rg * 16;
    const int tid = threadIdx.x;

    // row-axis interpolation coords (half = 64, denom = 127) — group-uniform
    const int j = y0 >> 6;
    int r0 = (j - 1) >> 1;             // matches Python floor division
    r0 = min(max(r0, 0), 7);
    const int r1 = min(r0 + 1, 7);

    // stage interleaved LUTs: entry i (i = tile*256 + idx) = {s0[i], s1[i]}
    {
        const float* lb = lut + (size_t)bc * 64 * NBINS;
        const fx4* s0 = (const fx4*)(lb + (size_t)r0 * 8 * NBINS);
        const fx4* s1 = (const fx4*)(lb + (size_t)r1 * 8 * NBINS);
        #pragma unroll
        for (int e = 0; e < 2; ++e) {
            const int i4 = e * 256 + tid;           // float4 index 0..511
            const fx4 a = s0[i4];
            const fx4 b = s1[i4];
            l01s[i4 * 2]     = (fx4){a.x, b.x, a.y, b.y};
            l01s[i4 * 2 + 1] = (fx4){a.z, b.z, a.w, b.w};
        }
    }
    __syncthreads();
    const fx2* lv = (const fx2*)l01s;

    // column-axis params for this thread's 4 columns (fixed across rows)
    int o0k[4], o1k[4];
    float wxk[4];
    #pragma unroll
    for (int k = 0; k < 4; ++k) {
        const int xx = tid * 4 + k;
        const int jc = xx >> 6, pc = xx & 63;
        int c0 = (jc - 1) >> 1;
        c0 = min(max(c0, 0), 7);
        o0k[k] = c0 * NBINS;
        o1k[k] = min(c0 + 1, 7) * NBINS;
        wxk[k] = (jc == 0) ? 1.0f
               : (float)((jc & 1) ? (127 - pc) : (63 - pc)) / 127.0f;
    }

    const bool jzero = (j == 0);
    const bool jodd  = (j & 1);
    const size_t rowbase = ((size_t)bc * 1024 + (size_t)y0) * 1024 + tid * 4;

    #pragma unroll 4
    for (int r = 0; r < 16; ++r) {
        const int p = (y0 + r) & 63;
        const float wy = jzero ? 1.0f
                       : (float)(jodd ? (127 - p) : (63 - p)) / 127.0f;

        const fx4 v = __builtin_nontemporal_load(
            (const fx4*)(x + rowbase + (size_t)r * 1024));
        const float vv[4] = {v.x, v.y, v.z, v.w};
        float res[4];
        #pragma unroll
        for (int k = 0; k < 4; ++k) {
            const int idx = min(max((int)(vv[k] * 255.0f), 0), 255);
            const fx2 G0 = lv[o0k[k] + idx];   // {g00, g10}
            const fx2 G1 = lv[o1k[k] + idx];   // {g01, g11}
            const float wx = wxk[k];
            const float a = fmaf(wx, G0.x - G1.x, G1.x);  // row r0 interp
            const float b = fmaf(wx, G0.y - G1.y, G1.y);  // row r1 interp
            res[k] = fmaf(wy, a - b, b) * (1.0f / 255.0f);
        }
        const fx4 o4 = {res[0], res[1], res[2], res[3]};
        __builtin_nontemporal_store(
            o4, (fx4*)(out + rowbase + (size_t)r * 1024));
    }
}

extern "C" void kernel_launch(void* const* d_in, const int* in_sizes, int n_in,
                              void* d_out, int out_size, void* d_ws, size_t ws_size,
                              hipStream_t stream) {
    const float* x = (const float*)d_in[0];
    float* out = (float*)d_out;
    float* lut = (float*)d_ws;   // 1536 * 256 floats = 1.57 MB

    clahe_hist_lut<<<1536, 256, 0, stream>>>(x, lut);
    // 24 planes * 64 sixteen-row groups = 1536 blocks (exactly 6 per CU)
    clahe_apply<<<24 * 64, 256, 0, stream>>>(x, lut, out);
}

// Round 5
// 179.437 us; speedup vs baseline: 1.3533x; 1.0586x over previous
//
#include <hip/hip_runtime.h>

#define NBINS 256
#define TILE  128          // tile is 128x128 -> 16384 pixels
#define CLIPV 2560u        // max(40 * 16384 // 256, 1)

typedef float fx4 __attribute__((ext_vector_type(4)));   // native vec for nontemporal ops

// ws layout: [0, 384K)   u8 LUT, 1536 tiles x 256 bins
//            [512K, +24M) u8 idx plane, same linear layout as x
#define IDX_OFF (512 * 1024)

// ---------------------------------------------------------------------------
// Kernel 1: per-tile histogram -> clip -> redistribute -> cumsum -> u8 LUT,
// and emit the per-pixel u8 idx plane (so apply never re-reads f32 x).
// One block per tile (1536), 256 threads (4 waves).
// 8-way bin-major sub-histograms: hs[bin*8 + (tid&7)] -> bank 8*(bin%4)+sub,
// exactly 2 lanes/bank expected (free per m136).
// ---------------------------------------------------------------------------
__global__ __launch_bounds__(256) void clahe_hist_lut(
        const float* __restrict__ x, unsigned char* __restrict__ lut8,
        unsigned int* __restrict__ idxw) {
    const int t   = blockIdx.x;          // tile id: ((b*3+c)*8+ty)*8+tx
    const int tid = threadIdx.x;

    __shared__ unsigned int hs[NBINS * 8];   // bin-major interleaved
    __shared__ int          scan[2][NBINS];
    __shared__ unsigned int wsum[4];

    #pragma unroll
    for (int k = 0; k < 8; ++k) hs[k * NBINS + tid] = 0u;
    __syncthreads();

    const int tx = t & 7;
    const int ty = (t >> 3) & 7;
    const int bc = t >> 6;
    const size_t pbase = ((size_t)bc * 1024 + (size_t)ty * TILE) * 1024
                       + (size_t)tx * TILE;
    const float* base = x + pbase;

    const int sub    = tid & 7;
    const int lane32 = tid & 31;   // float4 column within the tile row
    const int rgrp   = tid >> 5;   // 0..7 -> 8 rows covered per iteration
    #pragma unroll 4
    for (int rr = 0; rr < 16; ++rr) {
        const int row = rr * 8 + rgrp;
        const fx4 v = __builtin_nontemporal_load(
            (const fx4*)(base + (size_t)row * 1024 + lane32 * 4));
        const int b0 = min(max((int)(v.x * 256.0f), 0), 255);
        const int b1 = min(max((int)(v.y * 256.0f), 0), 255);
        const int b2 = min(max((int)(v.z * 256.0f), 0), 255);
        const int b3 = min(max((int)(v.w * 256.0f), 0), 255);
        atomicAdd(&hs[b0 * 8 + sub], 1u);
        atomicAdd(&hs[b1 * 8 + sub], 1u);
        atomicAdd(&hs[b2 * 8 + sub], 1u);
        atomicAdd(&hs[b3 * 8 + sub], 1u);
        // idx plane (u8): clip(x*255); packed 4 pixels -> one dword store
        const unsigned i0 = (unsigned)min(max((int)(v.x * 255.0f), 0), 255);
        const unsigned i1 = (unsigned)min(max((int)(v.y * 255.0f), 0), 255);
        const unsigned i2 = (unsigned)min(max((int)(v.z * 255.0f), 0), 255);
        const unsigned i3 = (unsigned)min(max((int)(v.w * 255.0f), 0), 255);
        idxw[(pbase + (size_t)row * 1024 + lane32 * 4) >> 2] =
            i0 | (i1 << 8) | (i2 << 16) | (i3 << 24);
    }
    __syncthreads();

    // gather the 8 sub-counts for bin `tid`
    const uint4* hp = (const uint4*)(&hs[tid * 8]);
    const uint4 ha = hp[0], hb = hp[1];
    const unsigned int total = ha.x + ha.y + ha.z + ha.w
                             + hb.x + hb.y + hb.z + hb.w;
    const unsigned int hv = min(total, CLIPV);
    unsigned int e = total - hv;               // excess clipped from this bin
    #pragma unroll
    for (int off = 32; off > 0; off >>= 1) e += __shfl_down(e, off, 64);
    if ((tid & 63) == 0) wsum[tid >> 6] = e;
    __syncthreads();
    const unsigned int E        = wsum[0] + wsum[1] + wsum[2] + wsum[3];
    const unsigned int add      = E >> 8;      // (clipped - residual)/256
    const unsigned int residual = E & 255u;    // clipped mod 256
    const int h2 = (int)(hv + add + ((unsigned)tid < residual ? 1u : 0u));

    // inclusive scan over 256 bins (Hillis-Steele, ping-pong)
    scan[0][tid] = h2;
    __syncthreads();
    int src = 0;
    #pragma unroll
    for (int off = 1; off < 256; off <<= 1) {
        int v = scan[src][tid];
        if (tid >= off) v += scan[src][tid - off];
        scan[src ^ 1][tid] = v;
        __syncthreads();
        src ^= 1;
    }
    const int cum = scan[src][tid];
    // 255/16384 = 255 * 2^-14: fp32 multiply is exact here (cum*255 < 2^22)
    // result is an exact integer 0..255 -> u8
    const float l = fminf((float)cum * (255.0f / 16384.0f), 255.0f);
    lut8[(size_t)t * NBINS + tid] = (unsigned char)floorf(l);
}

// ---------------------------------------------------------------------------
// Kernel 2: bilinear LUT interpolation from the u8 idx plane.
// One block per (bc, 16-row group); (r0,r1) uniform over the group.
// LDS pair-table: ptab[c0*256+i] packs {l_r0[c0][i], l_r0[c1][i],
// l_r1[c0][i], l_r1[c1][i]} as 4 u8 in one u32 -> ALL FOUR bilinear taps are
// a single ds_read_b32 per pixel. wx=1 / wy=1 edges remain exact because the
// factored blend g01 + 1.0*(g00-g01) is exact for small integers.
// ---------------------------------------------------------------------------
__global__ __launch_bounds__(256) void clahe_apply(
        const unsigned int* __restrict__ idxr,
        const unsigned char* __restrict__ lut8,
        float* __restrict__ out) {
    __shared__ unsigned int ptab[8 * NBINS];

    const int blk = blockIdx.x;
    const int bc  = blk >> 6;          // 64 16-row groups per image plane
    const int rg  = blk & 63;
    const int y0  = rg * 16;
    const int tid = threadIdx.x;

    // row-axis interpolation coords (half = 64, denom = 127) — group-uniform
    const int j = y0 >> 6;
    int r0 = (j - 1) >> 1;             // matches Python floor division
    r0 = min(max(r0, 0), 7);
    const int r1 = min(r0 + 1, 7);

    // build the pair table: 16 coalesced byte loads + 8 LDS stores per thread
    {
        const unsigned char* L0 = lut8 + (size_t)bc * 64 * NBINS + (size_t)r0 * 8 * NBINS;
        const unsigned char* L1 = lut8 + (size_t)bc * 64 * NBINS + (size_t)r1 * 8 * NBINS;
        unsigned a0[8], a1[8];
        #pragma unroll
        for (int c = 0; c < 8; ++c) {
            a0[c] = L0[c * NBINS + tid];
            a1[c] = L1[c * NBINS + tid];
        }
        #pragma unroll
        for (int c0 = 0; c0 < 8; ++c0) {
            const int c1 = min(c0 + 1, 7);
            ptab[c0 * NBINS + tid] =
                a0[c0] | (a0[c1] << 8) | (a1[c0] << 16) | (a1[c1] << 24);
        }
    }
    __syncthreads();

    // column-axis params for this thread's 4 columns (fixed across rows)
    int ock[4];
    float wxk[4];
    #pragma unroll
    for (int k = 0; k < 4; ++k) {
        const int xx = tid * 4 + k;
        const int jc = xx >> 6, pc = xx & 63;
        int c0 = (jc - 1) >> 1;
        c0 = min(max(c0, 0), 7);
        ock[k] = c0 * NBINS;
        wxk[k] = (jc == 0) ? 1.0f
               : (float)((jc & 1) ? (127 - pc) : (63 - pc)) / 127.0f;
    }

    const bool jzero = (j == 0);
    const bool jodd  = (j & 1);
    const size_t rowbase = ((size_t)bc * 1024 + (size_t)y0) * 1024 + tid * 4;

    #pragma unroll 4
    for (int r = 0; r < 16; ++r) {
        const int p = (y0 + r) & 63;
        const float wy = jzero ? 1.0f
                       : (float)(jodd ? (127 - p) : (63 - p)) / 127.0f;

        const unsigned pk = idxr[(rowbase + (size_t)r * 1024) >> 2];
        float res[4];
        #pragma unroll
        for (int k = 0; k < 4; ++k) {
            const unsigned id = (pk >> (8 * k)) & 0xffu;
            const unsigned e = ptab[ock[k] + id];
            const float g00 = (float)(e & 0xffu);
            const float g01 = (float)((e >> 8) & 0xffu);
            const float g10 = (float)((e >> 16) & 0xffu);
            const float g11 = (float)(e >> 24);
            const float wx = wxk[k];
            const float a = fmaf(wx, g00 - g01, g01);  // row r0 interp
            const float b = fmaf(wx, g10 - g11, g11);  // row r1 interp
            res[k] = fmaf(wy, a - b, b) * (1.0f / 255.0f);
        }
        const fx4 o4 = {res[0], res[1], res[2], res[3]};
        __builtin_nontemporal_store(
            o4, (fx4*)(out + rowbase + (size_t)r * 1024));
    }
}

extern "C" void kernel_launch(void* const* d_in, const int* in_sizes, int n_in,
                              void* d_out, int out_size, void* d_ws, size_t ws_size,
                              hipStream_t stream) {
    const float* x = (const float*)d_in[0];
    float* out = (float*)d_out;
    unsigned char* lut8 = (unsigned char*)d_ws;                       // 384 KB
    unsigned int*  idxw = (unsigned int*)((char*)d_ws + IDX_OFF);     // 24 MB

    clahe_hist_lut<<<1536, 256, 0, stream>>>(x, lut8, idxw);
    // 24 planes * 64 sixteen-row groups = 1536 blocks
    clahe_apply<<<24 * 64, 256, 0, stream>>>(idxw, lut8, out);
}